// Round 2
// baseline (317.535 us; speedup 1.0000x reference)
//
#include <hip/hip_runtime.h>

typedef unsigned short ushort_t;
typedef __attribute__((ext_vector_type(8))) __bf16 bf16x8;
typedef __attribute__((ext_vector_type(4))) float f32x4;

// B=32, N=128, INDIM=32, OUTDIM=64
// X: [32][128][128][32] f32; W: [32][64]; bias: [64]; n_nodes: [32] int
// X1t: [32][64][128][128] bf16  plane rows i, k=j contiguous
// X2t: [32][64][128][128] bf16  plane rows j, k=i contiguous
// out: [32][128][128][64] f32
//
// Masking contract:
//  - K1 writes ONLY rows r < n and col-parts part*32 < n. Within written
//    parts, cols t >= n are exact zeros (so k-tail [n,kmax) is exact zero).
//    Rows in [n,128) are workspace poison.
//  - K2' (mmtr) reads rows unguarded: garbage A-row j only corrupts D row j,
//    garbage B-row i only corrupts D col i (MFMA rows/cols are isolated);
//    both are masked to 0 in-register before staging. Output written directly
//    in [i][j][e] layout -> no Ct round-trip, no third kernel.

__device__ __forceinline__ ushort_t f32_to_bf16(float v) {
    unsigned ui = __float_as_uint(v);
    ui += 0x7fffu + ((ui >> 16) & 1u);   // RNE (finite only)
    return (ushort_t)(ui >> 16);
}

union FragU { bf16x8 f; ushort_t u[8]; };
union Pack4 { ushort_t us[4]; uint2 v; };

// K1 (merged passes): Linear(32->64)+bias+ReLU+mask via mfma_16x16x32.
// Grid 2048: blocks 0..1023 pass A (r=i, t=j contiguous), 1024..2047 pass B
// (r=j, t=i strided). Each block handles 4 consecutive r. r>=n rows are
// skipped entirely; t-tiles>=n skip loads+MFMA; copy-out truncated to
// col-parts < ceil32(n).
__global__ __launch_bounds__(256) void lin_mfma_kernel(
        const float* __restrict__ X,
        const float* __restrict__ W1, const float* __restrict__ b1v,
        const float* __restrict__ W2, const float* __restrict__ b2v,
        const int* __restrict__ n_nodes,
        ushort_t* __restrict__ X1t, ushort_t* __restrict__ X2t) {
    __shared__ ushort_t sO[64 * 136];
    const int blk = blockIdx.x;
    const int pass = blk >> 10;
    const int idx = blk & 1023;
    const int b = idx >> 5, rg = idx & 31;           // r-group of 4
    const int n = n_nodes[b];
    if (rg * 4 >= n) return;                         // block-uniform: nothing to write

    const float* W    = pass ? W2  : W1;
    const float* bias = pass ? b2v : b1v;
    ushort_t* Out     = pass ? X2t : X1t;
    const int rstride = pass ? 32 : 4096;
    const int tstride = pass ? 4096 : 32;

    const int u = threadIdx.x;
    const int w = u >> 6, l = u & 63;
    const int quad = l >> 4, lid = l & 15;

    // B-fragments: B[n=e][k=d], lane holds e=ni*16+lid, d=quad*8+j (L1-hot W).
    FragU bfrag[4];
    float bia[4];
    #pragma unroll
    for (int ni = 0; ni < 4; ++ni) {
        const int e = ni * 16 + lid;
        #pragma unroll
        for (int j = 0; j < 8; ++j)
            bfrag[ni].u[j] = f32_to_bf16(W[(quad * 8 + j) * 64 + e]);
        bia[ni] = bias[e];
    }

    for (int q = 0; q < 4; ++q) {
        const int r = rg * 4 + q;
        if (r >= n) break;                           // uniform (r ascending)
        {
            const float* Xb = X + (size_t)b * 524288 + (size_t)r * rstride;
            #pragma unroll
            for (int s = 0; s < 2; ++s) {
                const int mt = w * 2 + s;           // wave w owns m-tiles 2w,2w+1
                const int t0b = mt * 16 + quad * 4;
                if (mt * 16 < n) {
                    const int m = mt * 16 + lid;
                    const float* xr = Xb + (size_t)m * tstride + quad * 8;
                    float4 x0 = *(const float4*)xr;
                    float4 x1 = *(const float4*)(xr + 4);
                    FragU af;
                    af.u[0] = f32_to_bf16(x0.x); af.u[1] = f32_to_bf16(x0.y);
                    af.u[2] = f32_to_bf16(x0.z); af.u[3] = f32_to_bf16(x0.w);
                    af.u[4] = f32_to_bf16(x1.x); af.u[5] = f32_to_bf16(x1.y);
                    af.u[6] = f32_to_bf16(x1.z); af.u[7] = f32_to_bf16(x1.w);
                    #pragma unroll
                    for (int ni = 0; ni < 4; ++ni) {
                        f32x4 acc = {};
                        acc = __builtin_amdgcn_mfma_f32_16x16x32_bf16(
                            af.f, bfrag[ni].f, acc, 0, 0, 0);
                        const int e = ni * 16 + lid;
                        Pack4 pk;
                        #pragma unroll
                        for (int rgi = 0; rgi < 4; ++rgi) {
                            const int t = t0b + rgi;
                            float v = (t < n) ? fmaxf(acc[rgi] + bia[ni], 0.f) : 0.f;
                            pk.us[rgi] = f32_to_bf16(v);
                        }
                        *(uint2*)(sO + e * 136 + t0b) = pk.v;
                    }
                } else {
                    Pack4 pk; pk.us[0] = pk.us[1] = pk.us[2] = pk.us[3] = 0;
                    #pragma unroll
                    for (int ni = 0; ni < 4; ++ni)
                        *(uint2*)(sO + (ni * 16 + lid) * 136 + t0b) = pk.v;
                }
            }
        }
        __syncthreads();
        {   // copy-out: 64 e-rows, only col-parts < ceil32(n) (what K2' reads)
            const int e = u >> 2, part = u & 3;
            if (part * 32 < n) {
                ushort_t* gO = Out + ((size_t)(b * 64 + e) * 128 + r) * 128 + part * 32;
                const ushort_t* sRow = sO + e * 136 + part * 32;
                #pragma unroll
                for (int c = 0; c < 4; ++c)
                    *(uint4*)(gO + c * 8) = *(const uint4*)(sRow + c * 8);
            }
        }
        __syncthreads();
    }
}

// K2' (fused mm + transpose-out): block = b*16 + it*4 + jt, grid 512.
// Computes out[b][i0:i0+32][j0:j0+32][0:64]. Waves own e-pairs; 8 e-groups
// of 8 staged through sC[el][il][jl+pad36] (36 KiB), then coalesced float4
// writes directly to out. i>=n / j>=n masked in-register. Blocks fully
// outside the mask write their 256-KiB zero region with no reads.
__global__ __launch_bounds__(256) void mmtr_kernel(
        const ushort_t* __restrict__ X1t, const ushort_t* __restrict__ X2t,
        float* __restrict__ out, const int* __restrict__ n_nodes) {
    __shared__ float sC[8 * 32 * 36];                // [el][il][jl pad 36]
    const int blk = blockIdx.x;
    const int b = blk >> 4, it = (blk >> 2) & 3, jt = blk & 3;
    const int i0 = it * 32, j0 = jt * 32;
    const int n = n_nodes[b];
    const int u = threadIdx.x;
    float* base = out + ((size_t)((b * 128 + i0) * 128 + j0)) * 64;

    if (i0 >= n || j0 >= n) {                        // whole region is zeros
        float4 z = {0.f, 0.f, 0.f, 0.f};
        for (int il = 0; il < 32; ++il) {
            float4* r = (float4*)(base + (size_t)il * 8192);
            r[u] = z; r[u + 256] = z;
        }
        return;
    }

    const int w = u >> 6, l = u & 63;
    const int quad = l >> 4, lid = l & 15;
    const int kmax = (n + 31) & ~31;
    const size_t pb = (size_t)(b * 64) * 16384;
    const ushort_t* Aj = X2t + pb;                   // rows j, k contiguous
    const ushort_t* Bi = X1t + pb;                   // rows i, k contiguous

    for (int g = 0; g < 8; ++g) {
        const int e0 = g * 8 + w * 2;                // wave's e-pair e0, e0+1
        const ushort_t* A0 = Aj + (size_t)e0 * 16384;
        const ushort_t* B0 = Bi + (size_t)e0 * 16384;
        const ushort_t* A1 = A0 + 16384;
        const ushort_t* B1 = B0 + 16384;
        f32x4 acc[2][2][2] = {};                     // [ee][mj][ni]

        for (int k0 = 0; k0 < kmax; k0 += 32) {
            bf16x8 a0[2], a1[2], b0[2], b1[2];
            #pragma unroll
            for (int mj = 0; mj < 2; ++mj) {
                const size_t off = (size_t)(j0 + mj * 16 + lid) * 128 + k0 + quad * 8;
                a0[mj] = *(const bf16x8*)(A0 + off);
                a1[mj] = *(const bf16x8*)(A1 + off);
            }
            #pragma unroll
            for (int ni = 0; ni < 2; ++ni) {
                const size_t off = (size_t)(i0 + ni * 16 + lid) * 128 + k0 + quad * 8;
                b0[ni] = *(const bf16x8*)(B0 + off);
                b1[ni] = *(const bf16x8*)(B1 + off);
            }
            #pragma unroll
            for (int mj = 0; mj < 2; ++mj)
                #pragma unroll
                for (int ni = 0; ni < 2; ++ni) {
                    acc[0][mj][ni] = __builtin_amdgcn_mfma_f32_16x16x32_bf16(
                        a0[mj], b0[ni], acc[0][mj][ni], 0, 0, 0);
                    acc[1][mj][ni] = __builtin_amdgcn_mfma_f32_16x16x32_bf16(
                        a1[mj], b1[ni], acc[1][mj][ni], 0, 0, 0);
                }
        }

        // mask (i>=n, j>=n -> 0) and stage e-group into LDS
        #pragma unroll
        for (int ee = 0; ee < 2; ++ee) {
            const int el = w * 2 + ee;
            #pragma unroll
            for (int mj = 0; mj < 2; ++mj)
                #pragma unroll
                for (int ni = 0; ni < 2; ++ni) {
                    const int il = ni * 16 + lid;    // D col = i (lane)
                    const int jl = mj * 16 + quad * 4; // D row = j (reg-contig)
                    const bool iin = (i0 + il) < n;
                    float4 v;
                    v.x = (iin && (j0 + jl + 0) < n) ? acc[ee][mj][ni][0] : 0.f;
                    v.y = (iin && (j0 + jl + 1) < n) ? acc[ee][mj][ni][1] : 0.f;
                    v.z = (iin && (j0 + jl + 2) < n) ? acc[ee][mj][ni][2] : 0.f;
                    v.w = (iin && (j0 + jl + 3) < n) ? acc[ee][mj][ni][3] : 0.f;
                    *(float4*)(&sC[(el * 32 + il) * 36 + jl]) = v;
                }
        }
        __syncthreads();

        // copy-out e-group g: out[...][e = g*8 + elq*4 + t], coalesced float4
        #pragma unroll
        for (int rep = 0; rep < 8; ++rep) {
            const int idx = rep * 256 + u;           // b0=elq b1..5=jl b6..10=il
            const int elq = idx & 1, jl = (idx >> 1) & 31, il = idx >> 6;
            float4 vv;
            vv.x = sC[((elq * 4 + 0) * 32 + il) * 36 + jl];
            vv.y = sC[((elq * 4 + 1) * 32 + il) * 36 + jl];
            vv.z = sC[((elq * 4 + 2) * 32 + il) * 36 + jl];
            vv.w = sC[((elq * 4 + 3) * 32 + il) * 36 + jl];
            *(float4*)(base + (size_t)il * 8192 + jl * 64 + g * 8 + elq * 4) = vv;
        }
        __syncthreads();
    }
}

extern "C" void kernel_launch(void* const* d_in, const int* in_sizes, int n_in,
                              void* d_out, int out_size, void* d_ws, size_t ws_size,
                              hipStream_t stream) {
    const float* X  = (const float*)d_in[0];
    const float* W1 = (const float*)d_in[1];
    const float* b1 = (const float*)d_in[2];
    const float* W2 = (const float*)d_in[3];
    const float* b2 = (const float*)d_in[4];
    const int* nn   = (const int*)d_in[5];
    float* out = (float*)d_out;

    ushort_t* X1t = (ushort_t*)d_ws;          // 64 MiB
    ushort_t* X2t = X1t + 33554432;           // +64 MiB

    lin_mfma_kernel<<<2048, 256, 0, stream>>>(X, W1, b1, W2, b2, nn, X1t, X2t);
    mmtr_kernel<<<512, 256, 0, stream>>>(X1t, X2t, out, nn);
}

// Round 3
// 299.413 us; speedup vs baseline: 1.0605x; 1.0605x over previous
//
#include <hip/hip_runtime.h>

typedef unsigned short ushort_t;
typedef __attribute__((ext_vector_type(8))) __bf16 bf16x8;
typedef __attribute__((ext_vector_type(4))) float f32x4;

// B=32, N=128, INDIM=32, OUTDIM=64
// X: [32][128][128][32] f32; W: [32][64]; bias: [64]; n_nodes: [32] int
// X1t: [32][64][128][128] bf16  plane rows i, k=j contiguous
// X2t: [32][64][128][128] bf16  plane rows j, k=i contiguous
// Ct : aliases X1t (per-(b,e)-plane exclusive in K2)
// out: [32][128][128][64] f32
//
// Masking contract (same as R1, now produced by lin2):
//  - X1t rows i<n, cols [0,ceil32(n)) written; cols j in [n,kmax) EXACT ZERO.
//    Rows [n,128) unwritten poison (K2 reads up to ceil16(n); garbage rows
//    contaminate only C row j>=n / col i>=n, masked downstream).
//  - X2t symmetric (rows j<n, cols i in [n,kmax) exact zero).
//  - K2 stores only i<n rows, j-chunks c*8<n. K3 masks j>=n in the boundary
//    chunk on load.

__device__ __forceinline__ ushort_t f32_to_bf16(float v) {
    unsigned ui = __float_as_uint(v);
    ui += 0x7fffu + ((ui >> 16) & 1u);   // RNE (finite only)
    return (ushort_t)(ui >> 16);
}

union FragU { bf16x8 f; ushort_t u[8]; };
union Pack4 { ushort_t us[4]; uint2 v; };

#define SYP 1036  // LDS row stride (ushorts): %4==0 for uint2 align; word-stride 518 == 6 mod 32

// K1' (lin2): block = b*32 + eh*16 + it*4 + jt, grid 1024. Owns 32x32 (i,j)
// tile x 32 e (e-half). Two phases (W1->X1t i-major, W2->X2t j-major via LDS
// transpose). X read fully coalesced (2-KiB A-frag loads). No strided global
// access; all global writes 64-B chunks.
__global__ __launch_bounds__(256) void lin2_kernel(
        const float* __restrict__ X,
        const float* __restrict__ W1, const float* __restrict__ b1v,
        const float* __restrict__ W2, const float* __restrict__ b2v,
        const int* __restrict__ n_nodes,
        ushort_t* __restrict__ X1t, ushort_t* __restrict__ X2t) {
    __shared__ ushort_t sY[32 * SYP];                // 32 e-rows x 1024(+12) cols
    const int blk = blockIdx.x;
    const int b  = blk >> 5;
    const int eh = (blk >> 4) & 1;
    const int it = (blk >> 2) & 3, jt = blk & 3;
    const int i0 = it * 32, j0 = jt * 32;
    const int n = n_nodes[b];
    if (i0 >= n || j0 >= n) return;                  // tile never read downstream
    const int u = threadIdx.x;
    const int w = u >> 6, l = u & 63;
    const int quad = l >> 4, lid = l & 15;
    const int e0 = eh * 32;
    const float* Xb = X + (size_t)b * 524288;

    for (int p = 0; p < 2; ++p) {
        const float* W    = p ? W2  : W1;
        const float* bias = p ? b2v : b1v;
        ushort_t* Out     = p ? X2t : X1t;
        const int r0 = p ? j0 : i0;                  // out-plane row base
        const int c0 = p ? i0 : j0;                  // out-plane col base

        // B-frags: B[e][d], lane holds e=e0+ni*16+lid, d=quad*8+jj (L1-hot W)
        FragU bfrag[2];
        float bia[2];
        #pragma unroll
        for (int ni = 0; ni < 2; ++ni) {
            const int e = e0 + ni * 16 + lid;
            #pragma unroll
            for (int jj = 0; jj < 8; ++jj)
                bfrag[ni].u[jj] = f32_to_bf16(W[(quad * 8 + jj) * 64 + e]);
            bia[ni] = bias[e];
        }

        // 64 m-tiles of 16 tuples; wave w owns mt = w*16+mm.
        // m-tile mt: il = mt>>1 (const), jl = (mt&1)*16 + tuple-within-tile.
        for (int mm = 0; mm < 16; ++mm) {
            const int mt = w * 16 + mm;
            const int il = mt >> 1, jl0 = (mt & 1) * 16;
            const int gi = i0 + il;
            if (gi < n) {
                // A-frag: lane m=lid (tuple), k=quad*8..: contiguous 2 KiB
                const float* xr = Xb + (size_t)gi * 4096
                                     + (size_t)(j0 + jl0 + lid) * 32 + quad * 8;
                float4 x0 = *(const float4*)xr;
                float4 x1 = *(const float4*)(xr + 4);
                FragU af;
                af.u[0] = f32_to_bf16(x0.x); af.u[1] = f32_to_bf16(x0.y);
                af.u[2] = f32_to_bf16(x0.z); af.u[3] = f32_to_bf16(x0.w);
                af.u[4] = f32_to_bf16(x1.x); af.u[5] = f32_to_bf16(x1.y);
                af.u[6] = f32_to_bf16(x1.z); af.u[7] = f32_to_bf16(x1.w);
                #pragma unroll
                for (int ni = 0; ni < 2; ++ni) {
                    f32x4 acc = {};
                    acc = __builtin_amdgcn_mfma_f32_16x16x32_bf16(
                        af.f, bfrag[ni].f, acc, 0, 0, 0);
                    const int el = ni * 16 + lid;    // local e (D col = lid)
                    if (p == 0) {                    // i-major: 4 consec jl
                        Pack4 pk;
                        #pragma unroll
                        for (int rg = 0; rg < 4; ++rg) {
                            const int gj = j0 + jl0 + quad * 4 + rg;
                            float v = (gj < n) ? fmaxf(acc[rg] + bia[ni], 0.f) : 0.f;
                            pk.us[rg] = f32_to_bf16(v);
                        }
                        *(uint2*)(sY + el * SYP + il * 32 + jl0 + quad * 4) = pk.v;
                    } else {                         // j-major transpose scatter
                        #pragma unroll
                        for (int rg = 0; rg < 4; ++rg) {
                            const int jl = jl0 + quad * 4 + rg;
                            float v = ((j0 + jl) < n) ? fmaxf(acc[rg] + bia[ni], 0.f) : 0.f;
                            sY[el * SYP + jl * 32 + il] = f32_to_bf16(v);
                        }
                    }
                }
            } else if (p == 1) {
                // cols i in [n, kmax) of X2t must be EXACT zeros (k-tail)
                #pragma unroll
                for (int ni = 0; ni < 2; ++ni) {
                    const int el = ni * 16 + lid;
                    #pragma unroll
                    for (int rg = 0; rg < 4; ++rg)
                        sY[el * SYP + (jl0 + quad * 4 + rg) * 32 + il] = 0;
                }
            }
            // p==0, gi>=n: rows never copied out -> stale LDS harmless
        }
        __syncthreads();

        // copy-out: 32 e-rows x 32 plane-rows x 64 B; only rows r0+rl < n.
        // thread -> (el=(u>>2)&31, part=u&3, rl parity=u>>7): 64-B chunks.
        {
            const int el = (u >> 2) & 31, part = u & 3, rhalf = u >> 7;
            ushort_t* Ob = Out + ((size_t)(b * 64 + e0 + el) * 128 + r0) * 128
                               + c0 + part * 8;
            const ushort_t* Sb = sY + el * SYP + part * 8;
            for (int rr = 0; rr < 16; ++rr) {
                const int rl = rr * 2 + rhalf;       // wave-uniform guard
                if (r0 + rl < n)
                    *(uint4*)(Ob + (size_t)rl * 128) = *(const uint4*)(Sb + rl * 32);
            }
        }
        __syncthreads();
    }
}

// K2: per-(b,e) 128x128x128 bf16 MFMA, direct-from-global frags. k-loop
// truncated at ceil(n/32)*32; j-tiles/i-tiles >= n skip loads+MFMA. Rows in
// [n,ceil16(n)) are garbage -> contaminate only C[i>=n][*] and C[*][j>=n],
// which are either not stored or masked in K3. Stores only i<n, c*8<n.
__global__ __launch_bounds__(256) void mm_kernel(
        const ushort_t* __restrict__ X1t, const ushort_t* __restrict__ X2t,
        ushort_t* __restrict__ Ct, const int* __restrict__ n_nodes) {
    __shared__ ushort_t sC[128 * 136];
    const int blk = blockIdx.x;
    const size_t plane = (size_t)blk * 16384;        // blk = b*64+e
    const int n = n_nodes[blk >> 6];
    const int kmax = (n + 31) & ~31;
    const ushort_t* Aj = X2t + plane;
    const ushort_t* Bi = X1t + plane;
    const int u = threadIdx.x;
    const int w = u >> 6, l = u & 63;
    const int quad = l >> 4, lid = l & 15;
    const int wj = (w >> 1) * 64, wi = (w & 1) * 64;
    const bool anyA = (wj < n), anyB = (wi < n);
    bool aAct[4], bAct[4];
    #pragma unroll
    for (int mj = 0; mj < 4; ++mj) aAct[mj] = (wj + mj * 16) < n;
    #pragma unroll
    for (int ni = 0; ni < 4; ++ni) bAct[ni] = (wi + ni * 16) < n;
    f32x4 acc[4][4] = {};                            // [mj][ni]

    for (int k0 = 0; k0 < kmax; k0 += 32) {
        bf16x8 af[4], bfr[4];
        #pragma unroll
        for (int mj = 0; mj < 4; ++mj)
            if (aAct[mj] && anyB)
                af[mj] = *(const bf16x8*)(Aj + (size_t)(wj + mj * 16 + lid) * 128 + k0 + quad * 8);
        #pragma unroll
        for (int ni = 0; ni < 4; ++ni)
            if (bAct[ni] && anyA)
                bfr[ni] = *(const bf16x8*)(Bi + (size_t)(wi + ni * 16 + lid) * 128 + k0 + quad * 8);
        #pragma unroll
        for (int mj = 0; mj < 4; ++mj)
            #pragma unroll
            for (int ni = 0; ni < 4; ++ni)
                if (aAct[mj] && bAct[ni])
                    acc[mj][ni] = __builtin_amdgcn_mfma_f32_16x16x32_bf16(
                        af[mj], bfr[ni], acc[mj][ni], 0, 0, 0);
    }

    #pragma unroll
    for (int mj = 0; mj < 4; ++mj)
        #pragma unroll
        for (int ni = 0; ni < 4; ++ni) {
            const int j0 = wj + mj * 16 + quad * 4;  // C row = j (reg-contiguous)
            const int i  = wi + ni * 16 + lid;       // C col = i
            Pack4 pk;
            #pragma unroll
            for (int rg = 0; rg < 4; ++rg)
                pk.us[rg] = f32_to_bf16(acc[mj][ni][rg]);
            *(uint2*)(sC + i * 136 + j0) = pk.v;
        }
    __syncthreads();
    ushort_t* Cp = Ct + plane;
    #pragma unroll
    for (int it = 0; it < 8; ++it) {
        int idx = it * 256 + u;
        int i = idx >> 4, c = idx & 15;
        if (i < n && c * 8 < n)
            *(uint4*)(Cp + (size_t)idx * 8) = *(const uint4*)(sC + i * 136 + c * 8);
    }
}

// K3: block = (b, i). i>=n: write 32 KB zeros, no reads. Else gather
// Ct[b][e][i][j<n] (coalesced) into LDS sT[e][j] f32 stride 129, masking
// j>=n inside the boundary chunk and zero-filling j-tail chunks, then write
// out[b][i][:][:] as one contiguous 32-KB region.
__global__ __launch_bounds__(256) void tr_kernel(
        const ushort_t* __restrict__ Ct, float* __restrict__ out,
        const int* __restrict__ n_nodes) {
    __shared__ float sT[64 * 129];
    const int blk = blockIdx.x;                      // b*128 + i
    const int b = blk >> 7, i = blk & 127;
    const int u = threadIdx.x;
    const int n = n_nodes[b];
    float* ob = out + ((size_t)b * 16384 + (size_t)i * 128) * 64;

    if (i >= n) {                                    // block-uniform early-out
        float4 z = {0.f, 0.f, 0.f, 0.f};
        #pragma unroll
        for (int it = 0; it < 8; ++it)
            *(float4*)(ob + (size_t)(it * 256 + u) * 4) = z;
        return;
    }

    const ushort_t* Cb = Ct + (size_t)b * 1048576 + (size_t)i * 128;
    #pragma unroll
    for (int it = 0; it < 4; ++it) {
        int idx = it * 256 + u;
        int e = idx >> 4, c = idx & 15;
        float* dst = sT + e * 129 + c * 8;
        const int rem = n - c * 8;                   // #valid j in this chunk
        if (rem >= 8) {
            uint4 v = *(const uint4*)(Cb + (size_t)e * 16384 + c * 8);
            dst[0] = __uint_as_float(v.x << 16);
            dst[1] = __uint_as_float(v.x & 0xffff0000u);
            dst[2] = __uint_as_float(v.y << 16);
            dst[3] = __uint_as_float(v.y & 0xffff0000u);
            dst[4] = __uint_as_float(v.z << 16);
            dst[5] = __uint_as_float(v.z & 0xffff0000u);
            dst[6] = __uint_as_float(v.w << 16);
            dst[7] = __uint_as_float(v.w & 0xffff0000u);
        } else if (rem > 0) {                        // boundary chunk: mask j>=n
            uint4 v = *(const uint4*)(Cb + (size_t)e * 16384 + c * 8);
            float tmp[8];
            tmp[0] = __uint_as_float(v.x << 16);
            tmp[1] = __uint_as_float(v.x & 0xffff0000u);
            tmp[2] = __uint_as_float(v.y << 16);
            tmp[3] = __uint_as_float(v.y & 0xffff0000u);
            tmp[4] = __uint_as_float(v.z << 16);
            tmp[5] = __uint_as_float(v.z & 0xffff0000u);
            tmp[6] = __uint_as_float(v.w << 16);
            tmp[7] = __uint_as_float(v.w & 0xffff0000u);
            #pragma unroll
            for (int t = 0; t < 8; ++t) dst[t] = (t < rem) ? tmp[t] : 0.f;
        } else {
            #pragma unroll
            for (int t = 0; t < 8; ++t) dst[t] = 0.f;
        }
    }
    __syncthreads();

    #pragma unroll
    for (int it = 0; it < 8; ++it) {
        int idx = it * 256 + u;                      // float4 over flat (j,e)
        int j = idx >> 4, e0 = (idx & 15) * 4;
        float4 vv;
        vv.x = sT[(e0 + 0) * 129 + j];
        vv.y = sT[(e0 + 1) * 129 + j];
        vv.z = sT[(e0 + 2) * 129 + j];
        vv.w = sT[(e0 + 3) * 129 + j];
        *(float4*)(ob + (size_t)idx * 4) = vv;
    }
}

extern "C" void kernel_launch(void* const* d_in, const int* in_sizes, int n_in,
                              void* d_out, int out_size, void* d_ws, size_t ws_size,
                              hipStream_t stream) {
    const float* X  = (const float*)d_in[0];
    const float* W1 = (const float*)d_in[1];
    const float* b1 = (const float*)d_in[2];
    const float* W2 = (const float*)d_in[3];
    const float* b2 = (const float*)d_in[4];
    const int* nn   = (const int*)d_in[5];
    float* out = (float*)d_out;

    ushort_t* X1t = (ushort_t*)d_ws;          // 64 MiB
    ushort_t* X2t = X1t + 33554432;           // +64 MiB
    ushort_t* Ct  = X1t;                      // alias (per-plane exclusive in K2)

    lin2_kernel<<<1024, 256, 0, stream>>>(X, W1, b1, W2, b2, nn, X1t, X2t);
    mm_kernel<<<2048, 256, 0, stream>>>(X1t, X2t, Ct, nn);
    tr_kernel<<<4096, 256, 0, stream>>>(Ct, out, nn);
}

// Round 4
// 273.741 us; speedup vs baseline: 1.1600x; 1.0938x over previous
//
#include <hip/hip_runtime.h>

typedef unsigned short ushort_t;
typedef __attribute__((ext_vector_type(8))) __bf16 bf16x8;
typedef __attribute__((ext_vector_type(4))) float f32x4;

// B=32, N=128, INDIM=32, OUTDIM=64
// X: [32][128][128][32] f32; W: [32][64]; bias: [64]; n_nodes: [32] int
// X1t: [32][64][128][128] bf16  plane rows i, k=j contiguous
// X2t: [32][64][128][128] bf16  plane rows j, k=i contiguous
// Ct : aliases X1t (per-(b,e)-plane exclusive in K2)
// out: [32][128][128][64] f32
//
// Masking contract:
//  - K1 writes rows r < n, cols [0, kmax=ceil32(n)); cols t in [n,kmax) are
//    exact zeros. Rows [n,128) and cols >= kmax are unwritten poison.
//  - K2 reads rows < ceil16(n) (poison rows contaminate only C row j>=n /
//    col i>=n), k-loop < kmax; stores only i<n rows, j-chunks c*8<n.
//  - K3 masks j>=n inside the boundary chunk on load.

__device__ __forceinline__ ushort_t f32_to_bf16(float v) {
    unsigned ui = __float_as_uint(v);
    ui += 0x7fffu + ((ui >> 16) & 1u);   // RNE (finite only)
    return (ushort_t)(ui >> 16);
}

union FragU { bf16x8 f; ushort_t u[8]; };
union Pack4 { ushort_t us[4]; uint2 v; };

// K1: Linear(32->64)+bias+ReLU+mask via mfma_16x16x32, NO LDS / NO barriers.
// Grid 2048: blocks 0..1023 pass A (r=i, t=j contiguous), 1024..2047 pass B
// (r=j, t=i strided full-line gathers). Each block: 4 consecutive r. Waves
// fully independent; MFMA D-frag (e=lane, 4 consecutive t per quad) is stored
// directly as uint2 -> 16x32B segments per store instr (fine for 33 MB).
__global__ __launch_bounds__(256) void lin_mfma_kernel(
        const float* __restrict__ X,
        const float* __restrict__ W1, const float* __restrict__ b1v,
        const float* __restrict__ W2, const float* __restrict__ b2v,
        const int* __restrict__ n_nodes,
        ushort_t* __restrict__ X1t, ushort_t* __restrict__ X2t) {
    const int blk = blockIdx.x;
    const int pass = blk >> 10;
    const int idx = blk & 1023;
    const int b = idx >> 5, rg = idx & 31;           // r-group of 4
    const int n = n_nodes[b];
    if (rg * 4 >= n) return;                         // block-uniform: nothing to write
    const int kmax = (n + 31) & ~31;

    const float* W    = pass ? W2  : W1;
    const float* bias = pass ? b2v : b1v;
    ushort_t* Out     = pass ? X2t : X1t;
    const int rstride = pass ? 32 : 4096;
    const int tstride = pass ? 4096 : 32;

    const int u = threadIdx.x;
    const int w = u >> 6, l = u & 63;
    const int quad = l >> 4, lid = l & 15;

    // B-fragments: B[n=e][k=d], lane holds e=ni*16+lid, d=quad*8+j (L1-hot W).
    FragU bfrag[4];
    float bia[4];
    #pragma unroll
    for (int ni = 0; ni < 4; ++ni) {
        const int e = ni * 16 + lid;
        #pragma unroll
        for (int j = 0; j < 8; ++j)
            bfrag[ni].u[j] = f32_to_bf16(W[(quad * 8 + j) * 64 + e]);
        bia[ni] = bias[e];
    }

    for (int q = 0; q < 4; ++q) {
        const int r = rg * 4 + q;
        if (r >= n) break;                           // uniform (r ascending)
        const float* Xb = X + (size_t)b * 524288 + (size_t)r * rstride;
        ushort_t* Ob = Out + ((size_t)(b * 64) * 128 + r) * 128;  // + e*16384 + t
        #pragma unroll
        for (int s = 0; s < 2; ++s) {
            const int mt = w * 2 + s;               // wave w owns m-tiles 2w,2w+1
            const int t0b = mt * 16 + quad * 4;
            if (mt * 16 < n) {
                const int m = mt * 16 + lid;
                const float* xr = Xb + (size_t)m * tstride + quad * 8;
                float4 x0 = *(const float4*)xr;
                float4 x1 = *(const float4*)(xr + 4);
                FragU af;
                af.u[0] = f32_to_bf16(x0.x); af.u[1] = f32_to_bf16(x0.y);
                af.u[2] = f32_to_bf16(x0.z); af.u[3] = f32_to_bf16(x0.w);
                af.u[4] = f32_to_bf16(x1.x); af.u[5] = f32_to_bf16(x1.y);
                af.u[6] = f32_to_bf16(x1.z); af.u[7] = f32_to_bf16(x1.w);
                #pragma unroll
                for (int ni = 0; ni < 4; ++ni) {
                    f32x4 acc = {};
                    acc = __builtin_amdgcn_mfma_f32_16x16x32_bf16(
                        af.f, bfrag[ni].f, acc, 0, 0, 0);
                    const int e = ni * 16 + lid;
                    Pack4 pk;
                    #pragma unroll
                    for (int rgi = 0; rgi < 4; ++rgi) {
                        const int t = t0b + rgi;
                        float v = (t < n) ? fmaxf(acc[rgi] + bia[ni], 0.f) : 0.f;
                        pk.us[rgi] = f32_to_bf16(v);
                    }
                    *(uint2*)(Ob + (size_t)e * 16384 + t0b) = pk.v;
                }
            } else if (mt * 16 < kmax) {             // exact-zero k-tail [n,kmax)
                Pack4 pk; pk.us[0] = pk.us[1] = pk.us[2] = pk.us[3] = 0;
                #pragma unroll
                for (int ni = 0; ni < 4; ++ni)
                    *(uint2*)(Ob + (size_t)(ni * 16 + lid) * 16384 + t0b) = pk.v;
            }
        }
    }
}

// K2: per-(b,e) 128x128x128 bf16 MFMA, direct-from-global frags. k-loop
// truncated at kmax; j-tiles/i-tiles >= n skip loads+MFMA. Rows in
// [n,ceil16(n)) are garbage -> contaminate only C[i>=n][*] and C[*][j>=n],
// which are either not stored or masked in K3. Stores only i<n, c*8<n.
__global__ __launch_bounds__(256) void mm_kernel(
        const ushort_t* __restrict__ X1t, const ushort_t* __restrict__ X2t,
        ushort_t* __restrict__ Ct, const int* __restrict__ n_nodes) {
    __shared__ ushort_t sC[128 * 136];
    const int blk = blockIdx.x;
    const size_t plane = (size_t)blk * 16384;        // blk = b*64+e
    const int n = n_nodes[blk >> 6];
    const int kmax = (n + 31) & ~31;
    const ushort_t* Aj = X2t + plane;
    const ushort_t* Bi = X1t + plane;
    const int u = threadIdx.x;
    const int w = u >> 6, l = u & 63;
    const int quad = l >> 4, lid = l & 15;
    const int wj = (w >> 1) * 64, wi = (w & 1) * 64;
    const bool anyA = (wj < n), anyB = (wi < n);
    bool aAct[4], bAct[4];
    #pragma unroll
    for (int mj = 0; mj < 4; ++mj) aAct[mj] = (wj + mj * 16) < n;
    #pragma unroll
    for (int ni = 0; ni < 4; ++ni) bAct[ni] = (wi + ni * 16) < n;
    f32x4 acc[4][4] = {};                            // [mj][ni]

    for (int k0 = 0; k0 < kmax; k0 += 32) {
        bf16x8 af[4], bfr[4];
        #pragma unroll
        for (int mj = 0; mj < 4; ++mj)
            if (aAct[mj] && anyB)
                af[mj] = *(const bf16x8*)(Aj + (size_t)(wj + mj * 16 + lid) * 128 + k0 + quad * 8);
        #pragma unroll
        for (int ni = 0; ni < 4; ++ni)
            if (bAct[ni] && anyA)
                bfr[ni] = *(const bf16x8*)(Bi + (size_t)(wi + ni * 16 + lid) * 128 + k0 + quad * 8);
        #pragma unroll
        for (int mj = 0; mj < 4; ++mj)
            #pragma unroll
            for (int ni = 0; ni < 4; ++ni)
                if (aAct[mj] && bAct[ni])
                    acc[mj][ni] = __builtin_amdgcn_mfma_f32_16x16x32_bf16(
                        af[mj], bfr[ni], acc[mj][ni], 0, 0, 0);
    }

    #pragma unroll
    for (int mj = 0; mj < 4; ++mj)
        #pragma unroll
        for (int ni = 0; ni < 4; ++ni) {
            const int j0 = wj + mj * 16 + quad * 4;  // C row = j (reg-contiguous)
            const int i  = wi + ni * 16 + lid;       // C col = i
            Pack4 pk;
            #pragma unroll
            for (int rg = 0; rg < 4; ++rg)
                pk.us[rg] = f32_to_bf16(acc[mj][ni][rg]);
            *(uint2*)(sC + i * 136 + j0) = pk.v;
        }
    __syncthreads();
    ushort_t* Cp = Ct + plane;
    #pragma unroll
    for (int it = 0; it < 8; ++it) {
        int idx = it * 256 + u;
        int i = idx >> 4, c = idx & 15;
        if (i < n && c * 8 < n)
            *(uint4*)(Cp + (size_t)idx * 8) = *(const uint4*)(sC + i * 136 + c * 8);
    }
}

// K3: block = (b, i). i>=n: write 32 KB zeros, no reads. Else gather
// Ct[b][e][i][j<n] (coalesced) into LDS sT[e][j] f32 stride 129, masking
// j>=n inside the boundary chunk and zero-filling j-tail chunks, then write
// out[b][i][:][:] as one contiguous 32-KB region.
__global__ __launch_bounds__(256) void tr_kernel(
        const ushort_t* __restrict__ Ct, float* __restrict__ out,
        const int* __restrict__ n_nodes) {
    __shared__ float sT[64 * 129];
    const int blk = blockIdx.x;                      // b*128 + i
    const int b = blk >> 7, i = blk & 127;
    const int u = threadIdx.x;
    const int n = n_nodes[b];
    float* ob = out + ((size_t)b * 16384 + (size_t)i * 128) * 64;

    if (i >= n) {                                    // block-uniform early-out
        float4 z = {0.f, 0.f, 0.f, 0.f};
        #pragma unroll
        for (int it = 0; it < 8; ++it)
            *(float4*)(ob + (size_t)(it * 256 + u) * 4) = z;
        return;
    }

    const ushort_t* Cb = Ct + (size_t)b * 1048576 + (size_t)i * 128;
    #pragma unroll
    for (int it = 0; it < 4; ++it) {
        int idx = it * 256 + u;
        int e = idx >> 4, c = idx & 15;
        float* dst = sT + e * 129 + c * 8;
        const int rem = n - c * 8;                   // #valid j in this chunk
        if (rem >= 8) {
            uint4 v = *(const uint4*)(Cb + (size_t)e * 16384 + c * 8);
            dst[0] = __uint_as_float(v.x << 16);
            dst[1] = __uint_as_float(v.x & 0xffff0000u);
            dst[2] = __uint_as_float(v.y << 16);
            dst[3] = __uint_as_float(v.y & 0xffff0000u);
            dst[4] = __uint_as_float(v.z << 16);
            dst[5] = __uint_as_float(v.z & 0xffff0000u);
            dst[6] = __uint_as_float(v.w << 16);
            dst[7] = __uint_as_float(v.w & 0xffff0000u);
        } else if (rem > 0) {                        // boundary chunk: mask j>=n
            uint4 v = *(const uint4*)(Cb + (size_t)e * 16384 + c * 8);
            float tmp[8];
            tmp[0] = __uint_as_float(v.x << 16);
            tmp[1] = __uint_as_float(v.x & 0xffff0000u);
            tmp[2] = __uint_as_float(v.y << 16);
            tmp[3] = __uint_as_float(v.y & 0xffff0000u);
            tmp[4] = __uint_as_float(v.z << 16);
            tmp[5] = __uint_as_float(v.z & 0xffff0000u);
            tmp[6] = __uint_as_float(v.w << 16);
            tmp[7] = __uint_as_float(v.w & 0xffff0000u);
            #pragma unroll
            for (int t = 0; t < 8; ++t) dst[t] = (t < rem) ? tmp[t] : 0.f;
        } else {
            #pragma unroll
            for (int t = 0; t < 8; ++t) dst[t] = 0.f;
        }
    }
    __syncthreads();

    #pragma unroll
    for (int it = 0; it < 8; ++it) {
        int idx = it * 256 + u;                      // float4 over flat (j,e)
        int j = idx >> 4, e0 = (idx & 15) * 4;
        float4 vv;
        vv.x = sT[(e0 + 0) * 129 + j];
        vv.y = sT[(e0 + 1) * 129 + j];
        vv.z = sT[(e0 + 2) * 129 + j];
        vv.w = sT[(e0 + 3) * 129 + j];
        *(float4*)(ob + (size_t)idx * 4) = vv;
    }
}

extern "C" void kernel_launch(void* const* d_in, const int* in_sizes, int n_in,
                              void* d_out, int out_size, void* d_ws, size_t ws_size,
                              hipStream_t stream) {
    const float* X  = (const float*)d_in[0];
    const float* W1 = (const float*)d_in[1];
    const float* b1 = (const float*)d_in[2];
    const float* W2 = (const float*)d_in[3];
    const float* b2 = (const float*)d_in[4];
    const int* nn   = (const int*)d_in[5];
    float* out = (float*)d_out;

    ushort_t* X1t = (ushort_t*)d_ws;          // 64 MiB
    ushort_t* X2t = X1t + 33554432;           // +64 MiB
    ushort_t* Ct  = X1t;                      // alias (per-plane exclusive in K2)

    lin_mfma_kernel<<<2048, 256, 0, stream>>>(X, W1, b1, W2, b2, nn, X1t, X2t);
    mm_kernel<<<2048, 256, 0, stream>>>(X1t, X2t, Ct, nn);
    tr_kernel<<<4096, 256, 0, stream>>>(Ct, out, nn);
}